// Round 1
// baseline (146.263 us; speedup 1.0000x reference)
//
#include <hip/hip_runtime.h>
#include <stdint.h>

// Y = tanh(X @ W + b):  M=65536 (8*64*128), K=512, N=512, all fp32.
// bf16 MFMA (32x32x16), fp32 accumulate. 128x128 block tile, BK=64,
// 4 waves (2x2), wave tile 64x64 (2x2 frags of 32x32, acc = 4x f32x16).
// XOR-swizzled LDS ([row][64] bf16, byte ^= (row&7)<<4) for conflict-free
// ds_read_b128 fragment reads. W staged transposed with lane<->k-pair map
// (conflict-free b32 writes). Register prefetch of next K-step overlaps MFMA.

typedef short bf16x8 __attribute__((ext_vector_type(8)));
typedef float f32x16 __attribute__((ext_vector_type(16)));

#define KTOT 512
#define NTOT 512
#define BK   64

__device__ __forceinline__ uint32_t pk2(float a, float b) {
  uint16_t lo = __builtin_bit_cast(uint16_t, (__bf16)a);   // RNE
  uint16_t hi = __builtin_bit_cast(uint16_t, (__bf16)b);
  return (uint32_t)lo | ((uint32_t)hi << 16);
}

__device__ __forceinline__ float fast_tanh(float z) {
  // tanh(z) = 1 - 2/(exp(2z)+1); exp(2z) = exp2(z * 2*log2(e))
  float t = __builtin_amdgcn_exp2f(z * 2.8853900817779268f);
  return 1.0f - 2.0f * __builtin_amdgcn_rcpf(t + 1.0f);
}

struct Regs {
  float4 a0,a1,a2,a3,a4,a5,a6,a7;   // 32 fp32 of X (one K-step slice)
  float4 u0,u1,u2,u3;               // W row 2*kp   (16 n)
  float4 v0,v1,v2,v3;               // W row 2*kp+1 (16 n)
};

__global__ __launch_bounds__(256, 2)
void hotdd_kernel(const float* __restrict__ X, const float* __restrict__ W,
                  const float* __restrict__ Bv, float* __restrict__ Y) {
  __shared__ char Ab[128 * BK * 2];   // A tile  [m:128][k:64] bf16, swizzled
  __shared__ char Bb[128 * BK * 2];   // W tile^T [n:128][k:64] bf16, swizzled

  // XCD swizzle: d = a*32 + b*8 + c  ->  bm = a*8+c, bn = b.
  // The 4 bn-blocks sharing an X strip get dispatch indices {d, d+8, d+16, d+24}:
  // same XCD (round-robin), adjacent in time -> X re-reads hit that XCD's L2.
  const int d  = blockIdx.x;
  const int bm = ((d >> 5) << 3) | (d & 7);   // 0..511
  const int bn = (d >> 3) & 3;                // 0..3

  const int tid  = threadIdx.x;
  const int lane = tid & 63;
  const int wv   = tid >> 6;
  const int wr   = (wv >> 1) * 64;   // wave M offset in tile
  const int wc   = (wv & 1) * 64;    // wave N offset in tile
  const int lo5  = lane & 31;
  const int hi1  = lane >> 5;
  const int rs   = lo5 & 7;          // read-side swizzle key

  // ---- A staging map: thread -> (m = tid>>1, half ah of 64 k)
  const int am   = tid >> 1;
  const int ah   = tid & 1;
  const int amz  = am & 7;
  const int abase = am * 128;
  const float* Ag = X + (size_t)(bm * 128 + am) * KTOT + ah * 32;

  // ---- B staging map: lane kp=lo5 owns k = {2kp, 2kp+1}; 16 n per thread
  const int kp = lo5;
  const int ng = wv * 32 + hi1 * 16;               // local n base
  const float* Bg = W + (size_t)(2 * kp) * NTOT + bn * 128 + ng;

#define LOADR(R, K0) do {                                                     \
    const float* ap_ = Ag + (K0);                                             \
    R.a0 = *(const float4*)(ap_ +  0); R.a1 = *(const float4*)(ap_ +  4);     \
    R.a2 = *(const float4*)(ap_ +  8); R.a3 = *(const float4*)(ap_ + 12);     \
    R.a4 = *(const float4*)(ap_ + 16); R.a5 = *(const float4*)(ap_ + 20);     \
    R.a6 = *(const float4*)(ap_ + 24); R.a7 = *(const float4*)(ap_ + 28);     \
    const float* bp_ = Bg + (size_t)(K0) * NTOT;                              \
    R.u0 = *(const float4*)(bp_ +  0); R.u1 = *(const float4*)(bp_ +  4);     \
    R.u2 = *(const float4*)(bp_ +  8); R.u3 = *(const float4*)(bp_ + 12);     \
    R.v0 = *(const float4*)(bp_ + NTOT +  0); R.v1 = *(const float4*)(bp_ + NTOT +  4); \
    R.v2 = *(const float4*)(bp_ + NTOT +  8); R.v3 = *(const float4*)(bp_ + NTOT + 12); \
  } while (0)

  // A: 4x ds_write_b128, swizzled slot = (ah*4+j) ^ (am&7)
#define AST(R, J, P, Q)                                                       \
    *(uint4*)(Ab + abase + (((((ah << 2) + (J)) ^ amz)) << 4)) =              \
      make_uint4(pk2(R.P.x, R.P.y), pk2(R.P.z, R.P.w),                        \
                 pk2(R.Q.x, R.Q.y), pk2(R.Q.z, R.Q.w));
  // B: 16x ds_write_b32 (k-pair packed), banks spread by kp -> conflict-free
#define BST(R, I, UV, C)                                                      \
    *(uint32_t*)(Bb + (ng + (I)) * 128 + ((kp << 2) ^ (((I) & 7) << 4))) =    \
      pk2(R.u##UV.C, R.v##UV.C);

#define STORER(R) do {                                                        \
    AST(R, 0, a0, a1) AST(R, 1, a2, a3) AST(R, 2, a4, a5) AST(R, 3, a6, a7)   \
    BST(R, 0, 0, x) BST(R, 1, 0, y) BST(R, 2, 0, z) BST(R, 3, 0, w)           \
    BST(R, 4, 1, x) BST(R, 5, 1, y) BST(R, 6, 1, z) BST(R, 7, 1, w)           \
    BST(R, 8, 2, x) BST(R, 9, 2, y) BST(R,10, 2, z) BST(R,11, 2, w)           \
    BST(R,12, 3, x) BST(R,13, 3, y) BST(R,14, 3, z) BST(R,15, 3, w)           \
  } while (0)

  f32x16 acc00 = {}, acc01 = {}, acc10 = {}, acc11 = {};

  const char* Ard0 = Ab + (wr + lo5) * 128;
  const char* Ard1 = Ard0 + 32 * 128;
  const char* Brd0 = Bb + (wc + lo5) * 128;
  const char* Brd1 = Brd0 + 32 * 128;

#define MFMA_PHASE() do {                                                     \
    _Pragma("unroll")                                                         \
    for (int kk = 0; kk < 4; ++kk) {                                          \
      const int sb = ((((kk << 1) | hi1) ^ rs) << 4);                         \
      bf16x8 fa0 = *(const bf16x8*)(Ard0 + sb);                               \
      bf16x8 fa1 = *(const bf16x8*)(Ard1 + sb);                               \
      bf16x8 fb0 = *(const bf16x8*)(Brd0 + sb);                               \
      bf16x8 fb1 = *(const bf16x8*)(Brd1 + sb);                               \
      acc00 = __builtin_amdgcn_mfma_f32_32x32x16_bf16(fa0, fb0, acc00, 0,0,0);\
      acc01 = __builtin_amdgcn_mfma_f32_32x32x16_bf16(fa0, fb1, acc01, 0,0,0);\
      acc10 = __builtin_amdgcn_mfma_f32_32x32x16_bf16(fa1, fb0, acc10, 0,0,0);\
      acc11 = __builtin_amdgcn_mfma_f32_32x32x16_bf16(fa1, fb1, acc11, 0,0,0);\
    }                                                                         \
  } while (0)

  Regs r0, r1;
  LOADR(r0, 0);

#pragma unroll 1
  for (int s = 0; s < 8; s += 2) {
    STORER(r0);
    __syncthreads();
    LOADR(r1, (s + 1) * BK);        // prefetch overlaps MFMA below
    MFMA_PHASE();
    __syncthreads();
    STORER(r1);
    __syncthreads();
    if (s + 2 < 8) LOADR(r0, (s + 2) * BK);
    MFMA_PHASE();
    __syncthreads();
  }

  // ---- epilogue: bias + tanh + fp32 store
  const int gn0 = bn * 128 + wc + lo5;
  const int gn1 = gn0 + 32;
  const float bv0 = Bv[gn0];
  const float bv1 = Bv[gn1];

#define EPI(ACC, MI, GN, BVAL) do {                                           \
    _Pragma("unroll")                                                         \
    for (int r = 0; r < 16; ++r) {                                            \
      const int mloc = wr + (MI) * 32 + (hi1 << 2) + ((r >> 2) << 3) + (r & 3);\
      Y[(size_t)(bm * 128 + mloc) * NTOT + (GN)] = fast_tanh((ACC)[r] + (BVAL));\
    }                                                                         \
  } while (0)

  EPI(acc00, 0, gn0, bv0);
  EPI(acc01, 0, gn1, bv1);
  EPI(acc10, 1, gn0, bv0);
  EPI(acc11, 1, gn1, bv1);
}

extern "C" void kernel_launch(void* const* d_in, const int* in_sizes, int n_in,
                              void* d_out, int out_size, void* d_ws, size_t ws_size,
                              hipStream_t stream) {
  (void)in_sizes; (void)n_in; (void)out_size; (void)d_ws; (void)ws_size;
  const float* X = (const float*)d_in[0];
  const float* W = (const float*)d_in[1];
  const float* b = (const float*)d_in[2];
  float* Y = (float*)d_out;
  // grid: 512 M-blocks x 4 N-blocks = 2048
  hipLaunchKernelGGL(hotdd_kernel, dim3(2048), dim3(256), 0, stream, X, W, b, Y);
}